// Round 1
// baseline (346.675 us; speedup 1.0000x reference)
//
#include <hip/hip_runtime.h>
#include <hip/hip_bf16.h>
#include <math.h>

#define NODE_DIM 128
#define HIDDEN   64
#define N_NODES  100000
#define N_RELS   50
#define N_EDGESC 1000000
#define TEMPERATURE 0.5f
#define BIASF 0.0001f

// ---------------------------------------------------------------------------
// Prep: per-relation q_con[r][64] = rel_r @ W1_con + b1_con  and
//       s_edge[r] = MLP_edge(rel_r).  One 64-thread block per relation.
// ---------------------------------------------------------------------------
__global__ __launch_bounds__(64) void prep_rel(
    const float* __restrict__ rel_emb,
    const float* __restrict__ W1c, const float* __restrict__ b1c,
    const float* __restrict__ W1e, const float* __restrict__ b1e,
    const float* __restrict__ W2e, const float* __restrict__ b2e,
    float* __restrict__ qcon, float* __restrict__ sedge) {
  const int r = blockIdx.x;
  const int l = threadIdx.x;
  const float* x = rel_emb + (size_t)r * NODE_DIM;
  float ac = 0.f, ae = 0.f;
  #pragma unroll 8
  for (int k = 0; k < NODE_DIM; ++k) {
    float xk = x[k];
    ac = fmaf(xk, W1c[k * HIDDEN + l], ac);
    ae = fmaf(xk, W1e[k * HIDDEN + l], ae);
  }
  qcon[r * HIDDEN + l] = ac + b1c[l];
  float he = fmaxf(ae + b1e[l], 0.f) * W2e[l];
  #pragma unroll
  for (int off = 32; off > 0; off >>= 1) he += __shfl_down(he, off);
  if (l == 0) sedge[r] = he + b2e[0];
}

// ---------------------------------------------------------------------------
// Prep: p_con[n][64] = x_n @ W1_con   (bias folded into qcon).
// 1 wave per block; lane l owns W column l in 128 VGPRs; x_n is wave-uniform
// (blockIdx-derived) so the compiler can scalarize x loads to s_load.
// ---------------------------------------------------------------------------
__global__ __launch_bounds__(64) void prep_node_con(
    const float* __restrict__ all_embed,
    const float* __restrict__ W1,
    float* __restrict__ pcon) {
  const int l = threadIdx.x;
  float w[NODE_DIM];
  #pragma unroll
  for (int k = 0; k < NODE_DIM; ++k) w[k] = W1[k * HIDDEN + l];
  for (int n = blockIdx.x; n < N_NODES; n += gridDim.x) {
    const float* x = all_embed + (size_t)n * NODE_DIM;
    float acc = 0.f;
    #pragma unroll
    for (int k = 0; k < NODE_DIM; ++k) acc = fmaf(x[k], w[k], acc);
    pcon[(size_t)n * HIDDEN + l] = acc;
  }
}

// ---------------------------------------------------------------------------
// Prep: out[n] = relu(x_n @ W1 + b1) @ W2 + b2   (full per-node scalar MLP).
// Launched twice: (src) and (dst) weight sets.
// ---------------------------------------------------------------------------
__global__ __launch_bounds__(64) void prep_node_scalar(
    const float* __restrict__ all_embed,
    const float* __restrict__ W1, const float* __restrict__ b1,
    const float* __restrict__ W2, const float* __restrict__ b2,
    float* __restrict__ out) {
  const int l = threadIdx.x;
  float w[NODE_DIM];
  #pragma unroll
  for (int k = 0; k < NODE_DIM; ++k) w[k] = W1[k * HIDDEN + l];
  const float bias1 = b1[l];
  const float w2    = W2[l];
  const float bias2 = b2[0];
  for (int n = blockIdx.x; n < N_NODES; n += gridDim.x) {
    const float* x = all_embed + (size_t)n * NODE_DIM;
    float acc = 0.f;
    #pragma unroll
    for (int k = 0; k < NODE_DIM; ++k) acc = fmaf(x[k], w[k], acc);
    float h = fmaxf(acc + bias1, 0.f) * w2;
    #pragma unroll
    for (int off = 32; off > 0; off >>= 1) h += __shfl_down(h, off);
    if (l == 0) out[n] = h + bias2;
  }
}

// ---------------------------------------------------------------------------
// Edge kernel: 16 lanes per edge, lane sub handles hidden units 4*sub..4*sub+3.
// weight = relu(p[src]+p[dst]+q[rel]) @ W2c + b2c + s_src[src] + s_dst[dst]
//          + s_edge[rel];  out = sigmoid((gate(u) + weight)/T)
// ---------------------------------------------------------------------------
__global__ __launch_bounds__(256) void edge_kernel(
    const int*   __restrict__ edge_index,
    const int*   __restrict__ edge_type,
    const float* __restrict__ u,
    const float* __restrict__ pcon,
    const float* __restrict__ ssrc,
    const float* __restrict__ sdst,
    const float* __restrict__ qcon,
    const float* __restrict__ sedge,
    const float* __restrict__ W2c,
    const float* __restrict__ b2c,
    float* __restrict__ out) {
  const int tid = blockIdx.x * blockDim.x + threadIdx.x;
  const int e   = tid >> 4;
  const int sub = tid & 15;
  if (e >= N_EDGESC) return;

  const int src = edge_index[e];
  const int dst = edge_index[N_EDGESC + e];
  const int r   = edge_type[e];

  const float4 ps = *(const float4*)(pcon + (size_t)src * HIDDEN + sub * 4);
  const float4 pd = *(const float4*)(pcon + (size_t)dst * HIDDEN + sub * 4);
  const float4 q  = *(const float4*)(qcon + r * HIDDEN + sub * 4);
  const float4 w2 = *(const float4*)(W2c + sub * 4);

  float s = fmaxf(ps.x + pd.x + q.x, 0.f) * w2.x
          + fmaxf(ps.y + pd.y + q.y, 0.f) * w2.y
          + fmaxf(ps.z + pd.z + q.z, 0.f) * w2.z
          + fmaxf(ps.w + pd.w + q.w, 0.f) * w2.w;
  s += __shfl_xor(s, 1);
  s += __shfl_xor(s, 2);
  s += __shfl_xor(s, 4);
  s += __shfl_xor(s, 8);

  if (sub == 0) {
    float wsum = s + b2c[0] + ssrc[src] + sdst[dst] + sedge[r];
    float uu  = u[e];
    float eps = fmaf(2.f * BIASF - 1.f, uu, 1.f - BIASF);
    float g   = logf(eps) - log1pf(-eps);
    float z   = (g + wsum) * (1.f / TEMPERATURE);
    out[e] = 1.f / (1.f + expf(-z));
  }
}

extern "C" void kernel_launch(void* const* d_in, const int* in_sizes, int n_in,
                              void* d_out, int out_size, void* d_ws, size_t ws_size,
                              hipStream_t stream) {
  const int*   edge_index = (const int*)d_in[0];
  const int*   edge_type  = (const int*)d_in[1];
  const float* all_embed  = (const float*)d_in[2];
  const float* rel_emb    = (const float*)d_in[3];
  const float* u          = (const float*)d_in[4];
  const float* W1_src = (const float*)d_in[5];
  const float* b1_src = (const float*)d_in[6];
  const float* W2_src = (const float*)d_in[7];
  const float* b2_src = (const float*)d_in[8];
  const float* W1_dst = (const float*)d_in[9];
  const float* b1_dst = (const float*)d_in[10];
  const float* W2_dst = (const float*)d_in[11];
  const float* b2_dst = (const float*)d_in[12];
  const float* W1_edge = (const float*)d_in[13];
  const float* b1_edge = (const float*)d_in[14];
  const float* W2_edge = (const float*)d_in[15];
  const float* b2_edge = (const float*)d_in[16];
  const float* W1_con = (const float*)d_in[17];
  const float* b1_con = (const float*)d_in[18];
  const float* W2_con = (const float*)d_in[19];
  const float* b2_con = (const float*)d_in[20];

  float* ws    = (float*)d_ws;
  float* pcon  = ws;                                   // 100000*64
  float* ssrc  = pcon + (size_t)N_NODES * HIDDEN;      // 100000
  float* sdst  = ssrc + N_NODES;                       // 100000
  float* qcon  = sdst + N_NODES;                       // 50*64
  float* sedge = qcon + N_RELS * HIDDEN;               // 50

  prep_rel<<<N_RELS, 64, 0, stream>>>(rel_emb, W1_con, b1_con,
                                      W1_edge, b1_edge, W2_edge, b2_edge,
                                      qcon, sedge);
  prep_node_con<<<4096, 64, 0, stream>>>(all_embed, W1_con, pcon);
  prep_node_scalar<<<4096, 64, 0, stream>>>(all_embed, W1_src, b1_src, W2_src, b2_src, ssrc);
  prep_node_scalar<<<4096, 64, 0, stream>>>(all_embed, W1_dst, b1_dst, W2_dst, b2_dst, sdst);

  const int total_threads = N_EDGESC * 16;
  edge_kernel<<<(total_threads + 255) / 256, 256, 0, stream>>>(
      edge_index, edge_type, u, pcon, ssrc, sdst, qcon, sedge, W2_con, b2_con,
      (float*)d_out);
}

// Round 2
// 158.880 us; speedup vs baseline: 2.1820x; 2.1820x over previous
//
#include <hip/hip_runtime.h>
#include <hip/hip_bf16.h>
#include <hip/hip_fp16.h>
#include <math.h>

#define NODE_DIM 128
#define HIDDEN   64
#define N_NODES  100000
#define N_RELS   50
#define N_EDGESC 1000000
#define TEMPERATURE 0.5f
#define BIASF 0.0001f

// ---------------------------------------------------------------------------
// Per-relation: qcon[r][64] = rel_r @ W1_con + b1_con
//               srel[r]     = MLP_edge(rel_r) + b2_edge + b2_con
// ---------------------------------------------------------------------------
__global__ __launch_bounds__(64) void prep_rel(
    const float* __restrict__ rel_emb,
    const float* __restrict__ W1c, const float* __restrict__ b1c,
    const float* __restrict__ W1e, const float* __restrict__ b1e,
    const float* __restrict__ W2e, const float* __restrict__ b2e,
    const float* __restrict__ b2c,
    float* __restrict__ qcon, float* __restrict__ srel) {
  const int r = blockIdx.x;
  const int l = threadIdx.x;
  const float* x = rel_emb + (size_t)r * NODE_DIM;
  float ac = 0.f, ae = 0.f;
  #pragma unroll 8
  for (int k = 0; k < NODE_DIM; ++k) {
    float xk = x[k];
    ac = fmaf(xk, W1c[k * HIDDEN + l], ac);
    ae = fmaf(xk, W1e[k * HIDDEN + l], ae);
  }
  qcon[r * HIDDEN + l] = ac + b1c[l];
  float he = fmaxf(ae + b1e[l], 0.f) * W2e[l];
  #pragma unroll
  for (int off = 32; off > 0; off >>= 1) he += __shfl_xor(he, off);
  if (l == 0) srel[r] = he + b2e[0] + b2c[0];
}

// ---------------------------------------------------------------------------
// Fused node prep: one block = 3 waves; wave 0 -> pcon (fp16, no bias: folded
// into qcon), wave 1 -> ssrc scalar MLP, wave 2 -> sdst scalar MLP.
// 4 nodes per inner pass: amortizes W1 fetches 4x and gives 4 independent
// FMA chains. x loads are wave-uniform -> compiler scalarizes to s_load.
// ---------------------------------------------------------------------------
__global__ __launch_bounds__(192) void prep_fused(
    const float* __restrict__ all_embed,
    const float* __restrict__ W1c,
    const float* __restrict__ W1s, const float* __restrict__ b1s,
    const float* __restrict__ W2s, const float* __restrict__ b2s,
    const float* __restrict__ W1d, const float* __restrict__ b1d,
    const float* __restrict__ W2d, const float* __restrict__ b2d,
    __half* __restrict__ pcon,
    float* __restrict__ ssrc, float* __restrict__ sdst) {
  const int l  = threadIdx.x & 63;
  const int wv = threadIdx.x >> 6;  // 0=con, 1=src, 2=dst
  const float* __restrict__ W1 = (wv == 0) ? W1c : (wv == 1) ? W1s : W1d;
  const float* Bv1 = (wv == 2) ? b1d : b1s;
  const float* Wv2 = (wv == 2) ? W2d : W2s;
  const float* Bv2 = (wv == 2) ? b2d : b2s;
  const float bias1 = Bv1[l];
  const float w2l   = Wv2[l];
  const float bias2 = Bv2[0];
  float* sout = (wv == 2) ? sdst : ssrc;

  for (int nb = blockIdx.x * 4; nb < N_NODES; nb += gridDim.x * 4) {
    const float* x0 = all_embed + (size_t)nb * NODE_DIM;
    const float* x1 = x0 + NODE_DIM;
    const float* x2 = x1 + NODE_DIM;
    const float* x3 = x2 + NODE_DIM;
    float a0 = 0.f, a1 = 0.f, a2 = 0.f, a3 = 0.f;
    #pragma unroll
    for (int k = 0; k < NODE_DIM; ++k) {
      const float wk = W1[k * HIDDEN + l];
      a0 = fmaf(x0[k], wk, a0);
      a1 = fmaf(x1[k], wk, a1);
      a2 = fmaf(x2[k], wk, a2);
      a3 = fmaf(x3[k], wk, a3);
    }
    if (wv == 0) {
      pcon[(size_t)(nb + 0) * HIDDEN + l] = __float2half(a0);
      pcon[(size_t)(nb + 1) * HIDDEN + l] = __float2half(a1);
      pcon[(size_t)(nb + 2) * HIDDEN + l] = __float2half(a2);
      pcon[(size_t)(nb + 3) * HIDDEN + l] = __float2half(a3);
    } else {
      float h0 = fmaxf(a0 + bias1, 0.f) * w2l;
      float h1 = fmaxf(a1 + bias1, 0.f) * w2l;
      float h2 = fmaxf(a2 + bias1, 0.f) * w2l;
      float h3 = fmaxf(a3 + bias1, 0.f) * w2l;
      #pragma unroll
      for (int off = 32; off > 0; off >>= 1) {
        h0 += __shfl_xor(h0, off);
        h1 += __shfl_xor(h1, off);
        h2 += __shfl_xor(h2, off);
        h3 += __shfl_xor(h3, off);
      }
      if (l == 0) {
        sout[nb + 0] = h0 + bias2;
        sout[nb + 1] = h1 + bias2;
        sout[nb + 2] = h2 + bias2;
        sout[nb + 3] = h3 + bias2;
      }
    }
  }
}

// ---------------------------------------------------------------------------
// Edge kernel: 8 lanes/edge, lane sub covers hidden 8*sub..8*sub+7 (16 B fp16
// gather per endpoint). weight = relu(p[src]+p[dst]+q[rel]) @ W2c
//              + ssrc[src] + sdst[dst] + srel[rel]  (biases pre-folded)
// ---------------------------------------------------------------------------
__global__ __launch_bounds__(256) void edge_kernel(
    const int*   __restrict__ edge_index,
    const int*   __restrict__ edge_type,
    const float* __restrict__ u,
    const __half* __restrict__ pcon,
    const float* __restrict__ ssrc,
    const float* __restrict__ sdst,
    const float* __restrict__ qcon,
    const float* __restrict__ srel,
    const float* __restrict__ W2c,
    float* __restrict__ out) {
  const long long tid = (long long)blockIdx.x * blockDim.x + threadIdx.x;
  const int e   = (int)(tid >> 3);
  const int sub = (int)(tid & 7);
  if (e >= N_EDGESC) return;

  const int src = edge_index[e];
  const int dst = edge_index[N_EDGESC + e];
  const int r   = edge_type[e];

  uint4 us = *(const uint4*)(pcon + (size_t)src * HIDDEN + sub * 8);
  uint4 ut = *(const uint4*)(pcon + (size_t)dst * HIDDEN + sub * 8);
  const float4 q0 = *(const float4*)(qcon + r * HIDDEN + sub * 8);
  const float4 q1 = *(const float4*)(qcon + r * HIDDEN + sub * 8 + 4);
  const float4 w0 = *(const float4*)(W2c + sub * 8);
  const float4 w1 = *(const float4*)(W2c + sub * 8 + 4);

  const __half2* hs = (const __half2*)&us;
  const __half2* ht = (const __half2*)&ut;
  const float qv[8] = {q0.x, q0.y, q0.z, q0.w, q1.x, q1.y, q1.z, q1.w};
  const float wv[8] = {w0.x, w0.y, w0.z, w0.w, w1.x, w1.y, w1.z, w1.w};

  float s = 0.f;
  #pragma unroll
  for (int j = 0; j < 4; ++j) {
    float2 fs = __half22float2(hs[j]);
    float2 ft = __half22float2(ht[j]);
    s += fmaxf(fs.x + ft.x + qv[2 * j],     0.f) * wv[2 * j];
    s += fmaxf(fs.y + ft.y + qv[2 * j + 1], 0.f) * wv[2 * j + 1];
  }
  s += __shfl_xor(s, 1);
  s += __shfl_xor(s, 2);
  s += __shfl_xor(s, 4);

  if (sub == 0) {
    float wsum = s + ssrc[src] + sdst[dst] + srel[r];
    float uu   = u[e];
    float eps  = fmaf(2.f * BIASF - 1.f, uu, 1.f - BIASF);   // eps
    float ome  = fmaf(1.f - 2.f * BIASF, uu, BIASF);          // 1 - eps (exact form)
    float g    = logf(eps) - logf(ome);
    float z    = (g + wsum) * (1.f / TEMPERATURE);
    out[e] = 1.f / (1.f + expf(-z));
  }
}

extern "C" void kernel_launch(void* const* d_in, const int* in_sizes, int n_in,
                              void* d_out, int out_size, void* d_ws, size_t ws_size,
                              hipStream_t stream) {
  const int*   edge_index = (const int*)d_in[0];
  const int*   edge_type  = (const int*)d_in[1];
  const float* all_embed  = (const float*)d_in[2];
  const float* rel_emb    = (const float*)d_in[3];
  const float* u          = (const float*)d_in[4];
  const float* W1_src = (const float*)d_in[5];
  const float* b1_src = (const float*)d_in[6];
  const float* W2_src = (const float*)d_in[7];
  const float* b2_src = (const float*)d_in[8];
  const float* W1_dst = (const float*)d_in[9];
  const float* b1_dst = (const float*)d_in[10];
  const float* W2_dst = (const float*)d_in[11];
  const float* b2_dst = (const float*)d_in[12];
  const float* W1_edge = (const float*)d_in[13];
  const float* b1_edge = (const float*)d_in[14];
  const float* W2_edge = (const float*)d_in[15];
  const float* b2_edge = (const float*)d_in[16];
  const float* W1_con = (const float*)d_in[17];
  const float* b1_con = (const float*)d_in[18];
  const float* W2_con = (const float*)d_in[19];
  const float* b2_con = (const float*)d_in[20];

  char* ws = (char*)d_ws;
  __half* pcon = (__half*)ws;                                   // 100000*64 fp16
  float*  ssrc = (float*)(ws + (size_t)N_NODES * HIDDEN * 2);   // 100000
  float*  sdst = ssrc + N_NODES;                                // 100000
  float*  qcon = sdst + N_NODES;                                // 50*64
  float*  srel = qcon + N_RELS * HIDDEN;                        // 50

  prep_rel<<<N_RELS, 64, 0, stream>>>(rel_emb, W1_con, b1_con,
                                      W1_edge, b1_edge, W2_edge, b2_edge, b2_con,
                                      qcon, srel);
  prep_fused<<<2560, 192, 0, stream>>>(all_embed, W1_con,
                                       W1_src, b1_src, W2_src, b2_src,
                                       W1_dst, b1_dst, W2_dst, b2_dst,
                                       pcon, ssrc, sdst);
  const long long total_threads = (long long)N_EDGESC * 8;
  edge_kernel<<<(int)((total_threads + 255) / 256), 256, 0, stream>>>(
      edge_index, edge_type, u, pcon, ssrc, sdst, qcon, srel, W2_con,
      (float*)d_out);
}

// Round 3
// 71.465 us; speedup vs baseline: 4.8510x; 2.2232x over previous
//
#include <hip/hip_runtime.h>
#include <hip/hip_bf16.h>
#include <hip/hip_fp16.h>
#include <math.h>

#define NODE_DIM 128
#define HIDDEN   64
#define N_NODES  100000
#define N_RELS   50
#define N_EDGESC 1000000
#define TEMPERATURE 0.5f
#define BIASF 0.0001f

typedef __attribute__((ext_vector_type(8))) _Float16 f16x8;
typedef __attribute__((ext_vector_type(4))) float    f32x4;

// ---------------------------------------------------------------------------
// Kernel 1 (tiny): blocks 0..95 convert W1_{con,src,dst} f32 [128][64] into
// wt f16 [n=192][k=128] transposed + XOR-swizzled (k ^= (n&7)<<3) so the GEMM
// can global_load_lds it linearly and ds_read_b128 conflict-free.
// Blocks 96.. : per-relation qcon[r][64] = rel_r @ W1_con + b1_con and
// srel[r] = MLP_edge(rel_r) + b2_edge + b2_con.  (4 relations per block)
// ---------------------------------------------------------------------------
__global__ __launch_bounds__(256) void prep_small(
    const float* __restrict__ W1c, const float* __restrict__ W1s,
    const float* __restrict__ W1d,
    const float* __restrict__ rel_emb,
    const float* __restrict__ b1c,
    const float* __restrict__ W1e, const float* __restrict__ b1e,
    const float* __restrict__ W2e, const float* __restrict__ b2e,
    const float* __restrict__ b2c,
    _Float16* __restrict__ wt,
    float* __restrict__ qcon, float* __restrict__ srel) {
  const int bid = blockIdx.x;
  if (bid < 96) {
    const int tid = bid * 256 + threadIdx.x;     // 0..24575
    const int k = tid / 192;
    const int n = tid % 192;
    const float* W = (n < 64) ? W1c : (n < 128) ? W1s : W1d;
    const float v = W[k * HIDDEN + (n & 63)];
    const int ks = k ^ ((n & 7) << 3);
    wt[n * NODE_DIM + ks] = (_Float16)v;
  } else {
    const int r = (bid - 96) * 4 + (threadIdx.x >> 6);
    const int l = threadIdx.x & 63;
    if (r >= N_RELS) return;
    const float* x = rel_emb + (size_t)r * NODE_DIM;
    float ac = 0.f, ae = 0.f;
    #pragma unroll 8
    for (int k = 0; k < NODE_DIM; ++k) {
      float xk = x[k];
      ac = fmaf(xk, W1c[k * HIDDEN + l], ac);
      ae = fmaf(xk, W1e[k * HIDDEN + l], ae);
    }
    qcon[r * HIDDEN + l] = ac + b1c[l];
    float he = fmaxf(ae + b1e[l], 0.f) * W2e[l];
    #pragma unroll
    for (int off = 32; off > 0; off >>= 1) he += __shfl_xor(he, off);
    if (l == 0) srel[r] = he + b2e[0] + b2c[0];
  }
}

// ---------------------------------------------------------------------------
// Kernel 2: MFMA prep GEMM.  C[100000 x 192] = all_embed @ [W1c|W1s|W1d].
// Block = 8 waves, BM=128 (wave w -> rows m0..m0+15). K=128 via 4 MFMA steps.
// Cols 0..63 -> pcon (fp16, bias folded into qcon); 64..127 -> fused
// relu(.+b1s)@W2s+b2s -> ssrc; 128..191 -> sdst.
// ---------------------------------------------------------------------------
__global__ __launch_bounds__(512) void prep_gemm(
    const float* __restrict__ x,
    const _Float16* __restrict__ wt,      // [192][128] f16, k XOR-swizzled
    const float* __restrict__ b1s, const float* __restrict__ W2s,
    const float* __restrict__ b2s,
    const float* __restrict__ b1d, const float* __restrict__ W2d,
    const float* __restrict__ b2d,
    __half* __restrict__ pcon,
    float* __restrict__ ssrc, float* __restrict__ sdst) {
  __shared__ _Float16 bl[192 * NODE_DIM];       // 48 KiB
  const int wv = threadIdx.x >> 6;              // 0..7
  const int l  = threadIdx.x & 63;
  const int hi = l >> 4;
  const int c  = l & 15;

  // Stage wt -> LDS linearly: 48 chunks of 1 KiB (64 lanes x 16 B); wave w
  // takes chunks w, w+8, ... (LDS dest = uniform base + lane*16).
  {
    const char* g = (const char*)wt;
    #pragma unroll
    for (int i = 0; i < 6; ++i) {
      const int chunk = (i * 8 + wv) << 10;
      __builtin_amdgcn_global_load_lds(
          (const __attribute__((address_space(1))) void*)(g + chunk + l * 16),
          (__attribute__((address_space(3))) void*)((char*)bl + chunk),
          16, 0, 0);
    }
  }

  // A fragments: lane holds row m0+(l&15), k = s*32 + hi*8 .. +7 (f32->f16).
  const int m0   = blockIdx.x * 128 + wv * 16;
  const int arow = m0 + c;
  const int rowc = arow < N_NODES ? arow : N_NODES - 1;
  const float* xr = x + (size_t)rowc * NODE_DIM + hi * 8;
  f16x8 a[4];
  #pragma unroll
  for (int s = 0; s < 4; ++s) {
    float4 u0 = *(const float4*)(xr + s * 32);
    float4 u1 = *(const float4*)(xr + s * 32 + 4);
    f16x8 av;
    av[0] = (_Float16)u0.x; av[1] = (_Float16)u0.y;
    av[2] = (_Float16)u0.z; av[3] = (_Float16)u0.w;
    av[4] = (_Float16)u1.x; av[5] = (_Float16)u1.y;
    av[6] = (_Float16)u1.z; av[7] = (_Float16)u1.w;
    a[s] = av;
  }

  __syncthreads();   // drains global_load_lds (vmcnt) + barrier

  f32x4 acc[12];
  #pragma unroll
  for (int i = 0; i < 12; ++i) acc[i] = (f32x4){0.f, 0.f, 0.f, 0.f};

  #pragma unroll
  for (int tt = 0; tt < 12; ++tt) {
    const int n = tt * 16 + c;
    const int nbase = n * NODE_DIM;
    #pragma unroll
    for (int s = 0; s < 4; ++s) {
      const int ks = (s * 32 + hi * 8) ^ ((n & 7) << 3);
      f16x8 b = *(const f16x8*)(&bl[nbase + ks]);
      acc[tt] = __builtin_amdgcn_mfma_f32_16x16x32_f16(a[s], b, acc[tt], 0, 0, 0);
    }
  }

  // ---- epilogue ----
  // con: D[row][col]: col = c (hidden tt*16+c), row = hi*4+g
  #pragma unroll
  for (int tt = 0; tt < 4; ++tt) {
    #pragma unroll
    for (int g = 0; g < 4; ++g) {
      const int row = m0 + hi * 4 + g;
      if (row < N_NODES)
        pcon[(size_t)row * HIDDEN + tt * 16 + c] = __float2half(acc[tt][g]);
    }
  }
  // src / dst: fused relu(acc+b1)*W2, reduce over 64 cols (4 tiles x 16 lanes)
  float ps[4] = {0.f, 0.f, 0.f, 0.f};
  float pd[4] = {0.f, 0.f, 0.f, 0.f};
  #pragma unroll
  for (int tt = 0; tt < 4; ++tt) {
    const int h = tt * 16 + c;
    const float b1sv = b1s[h], w2sv = W2s[h];
    const float b1dv = b1d[h], w2dv = W2d[h];
    #pragma unroll
    for (int g = 0; g < 4; ++g) {
      ps[g] += fmaxf(acc[4 + tt][g] + b1sv, 0.f) * w2sv;
      pd[g] += fmaxf(acc[8 + tt][g] + b1dv, 0.f) * w2dv;
    }
  }
  #pragma unroll
  for (int off = 1; off < 16; off <<= 1) {
    #pragma unroll
    for (int g = 0; g < 4; ++g) {
      ps[g] += __shfl_xor(ps[g], off);
      pd[g] += __shfl_xor(pd[g], off);
    }
  }
  if (c == 0) {
    const float bs = b2s[0], bd = b2d[0];
    #pragma unroll
    for (int g = 0; g < 4; ++g) {
      const int row = m0 + hi * 4 + g;
      if (row < N_NODES) { ssrc[row] = ps[g] + bs; sdst[row] = pd[g] + bd; }
    }
  }
}

// ---------------------------------------------------------------------------
// Edge kernel: 8 lanes/edge; weight = relu(p[src]+p[dst]+q[r]) @ W2c
//            + ssrc[src] + sdst[dst] + srel[r]   (biases pre-folded)
// ---------------------------------------------------------------------------
__global__ __launch_bounds__(256) void edge_kernel(
    const int*   __restrict__ edge_index,
    const int*   __restrict__ edge_type,
    const float* __restrict__ u,
    const __half* __restrict__ pcon,
    const float* __restrict__ ssrc,
    const float* __restrict__ sdst,
    const float* __restrict__ qcon,
    const float* __restrict__ srel,
    const float* __restrict__ W2c,
    float* __restrict__ out) {
  const long long tid = (long long)blockIdx.x * blockDim.x + threadIdx.x;
  const int e   = (int)(tid >> 3);
  const int sub = (int)(tid & 7);
  if (e >= N_EDGESC) return;

  const int src = edge_index[e];
  const int dst = edge_index[N_EDGESC + e];
  const int r   = edge_type[e];

  uint4 us = *(const uint4*)(pcon + (size_t)src * HIDDEN + sub * 8);
  uint4 ut = *(const uint4*)(pcon + (size_t)dst * HIDDEN + sub * 8);
  const float4 q0 = *(const float4*)(qcon + r * HIDDEN + sub * 8);
  const float4 q1 = *(const float4*)(qcon + r * HIDDEN + sub * 8 + 4);
  const float4 w0 = *(const float4*)(W2c + sub * 8);
  const float4 w1 = *(const float4*)(W2c + sub * 8 + 4);

  const __half2* hs = (const __half2*)&us;
  const __half2* ht = (const __half2*)&ut;
  const float qv[8] = {q0.x, q0.y, q0.z, q0.w, q1.x, q1.y, q1.z, q1.w};
  const float wv[8] = {w0.x, w0.y, w0.z, w0.w, w1.x, w1.y, w1.z, w1.w};

  float s = 0.f;
  #pragma unroll
  for (int j = 0; j < 4; ++j) {
    float2 fs = __half22float2(hs[j]);
    float2 ft = __half22float2(ht[j]);
    s += fmaxf(fs.x + ft.x + qv[2 * j],     0.f) * wv[2 * j];
    s += fmaxf(fs.y + ft.y + qv[2 * j + 1], 0.f) * wv[2 * j + 1];
  }
  s += __shfl_xor(s, 1);
  s += __shfl_xor(s, 2);
  s += __shfl_xor(s, 4);

  if (sub == 0) {
    float wsum = s + ssrc[src] + sdst[dst] + srel[r];
    float uu   = u[e];
    float eps  = fmaf(2.f * BIASF - 1.f, uu, 1.f - BIASF);   // eps
    float ome  = fmaf(1.f - 2.f * BIASF, uu, BIASF);         // 1 - eps
    float g    = logf(eps) - logf(ome);
    float z    = (g + wsum) * (1.f / TEMPERATURE);
    out[e] = 1.f / (1.f + expf(-z));
  }
}

extern "C" void kernel_launch(void* const* d_in, const int* in_sizes, int n_in,
                              void* d_out, int out_size, void* d_ws, size_t ws_size,
                              hipStream_t stream) {
  const int*   edge_index = (const int*)d_in[0];
  const int*   edge_type  = (const int*)d_in[1];
  const float* all_embed  = (const float*)d_in[2];
  const float* rel_emb    = (const float*)d_in[3];
  const float* u          = (const float*)d_in[4];
  const float* W1_src = (const float*)d_in[5];
  const float* b1_src = (const float*)d_in[6];
  const float* W2_src = (const float*)d_in[7];
  const float* b2_src = (const float*)d_in[8];
  const float* W1_dst = (const float*)d_in[9];
  const float* b1_dst = (const float*)d_in[10];
  const float* W2_dst = (const float*)d_in[11];
  const float* b2_dst = (const float*)d_in[12];
  const float* W1_edge = (const float*)d_in[13];
  const float* b1_edge = (const float*)d_in[14];
  const float* W2_edge = (const float*)d_in[15];
  const float* b2_edge = (const float*)d_in[16];
  const float* W1_con = (const float*)d_in[17];
  const float* b1_con = (const float*)d_in[18];
  const float* W2_con = (const float*)d_in[19];
  const float* b2_con = (const float*)d_in[20];

  char* ws = (char*)d_ws;
  __half*   pcon = (__half*)ws;                                  // 100000*64 fp16
  float*    ssrc = (float*)(ws + (size_t)N_NODES * HIDDEN * 2);  // 100000
  float*    sdst = ssrc + N_NODES;                               // 100000
  float*    qcon = sdst + N_NODES;                               // 50*64
  float*    srel = qcon + N_RELS * HIDDEN;                       // 50
  _Float16* wt   = (_Float16*)(srel + N_RELS);                   // 192*128 f16

  prep_small<<<96 + (N_RELS + 3) / 4, 256, 0, stream>>>(
      W1_con, W1_src, W1_dst, rel_emb, b1_con,
      W1_edge, b1_edge, W2_edge, b2_edge, b2_con,
      wt, qcon, srel);

  prep_gemm<<<(N_NODES + 127) / 128, 512, 0, stream>>>(
      all_embed, wt,
      b1_src, W2_src, b2_src, b1_dst, W2_dst, b2_dst,
      pcon, ssrc, sdst);

  const long long total_threads = (long long)N_EDGESC * 8;
  edge_kernel<<<(int)((total_threads + 255) / 256), 256, 0, stream>>>(
      edge_index, edge_type, u, pcon, ssrc, sdst, qcon, srel, W2_con,
      (float*)d_out);
}

// Round 4
// 71.145 us; speedup vs baseline: 4.8728x; 1.0045x over previous
//
#include <hip/hip_runtime.h>
#include <hip/hip_bf16.h>
#include <hip/hip_fp16.h>
#include <math.h>

#define NODE_DIM 128
#define HIDDEN   64
#define N_NODES  100000
#define N_RELS   50
#define N_EDGESC 1000000
#define TEMPERATURE 0.5f
#define BIASF 0.0001f

typedef __attribute__((ext_vector_type(8))) _Float16 f16x8;
typedef __attribute__((ext_vector_type(4))) float    f32x4;

// ---------------------------------------------------------------------------
// Kernel 1 (tiny): blocks 0..95 convert W1_{con,src,dst} f32 [128][64] into
// wt f16 [n=192][k=128] transposed + XOR-swizzled (k ^= (n&7)<<3) so the GEMM
// can global_load_lds it linearly and ds_read_b128 conflict-free.
// Blocks 96.. : per-relation qcon[r][64] = rel_r @ W1_con + b1_con and
// srel[r] = MLP_edge(rel_r) + b2_edge + b2_con.  (4 relations per block)
// ---------------------------------------------------------------------------
__global__ __launch_bounds__(256) void prep_small(
    const float* __restrict__ W1c, const float* __restrict__ W1s,
    const float* __restrict__ W1d,
    const float* __restrict__ rel_emb,
    const float* __restrict__ b1c,
    const float* __restrict__ W1e, const float* __restrict__ b1e,
    const float* __restrict__ W2e, const float* __restrict__ b2e,
    const float* __restrict__ b2c,
    _Float16* __restrict__ wt,
    float* __restrict__ qcon, float* __restrict__ srel) {
  const int bid = blockIdx.x;
  if (bid < 96) {
    const int tid = bid * 256 + threadIdx.x;     // 0..24575
    const int k = tid / 192;
    const int n = tid % 192;
    const float* W = (n < 64) ? W1c : (n < 128) ? W1s : W1d;
    const float v = W[k * HIDDEN + (n & 63)];
    const int ks = k ^ ((n & 7) << 3);
    wt[n * NODE_DIM + ks] = (_Float16)v;
  } else {
    const int r = (bid - 96) * 4 + (threadIdx.x >> 6);
    const int l = threadIdx.x & 63;
    if (r >= N_RELS) return;
    const float* x = rel_emb + (size_t)r * NODE_DIM;
    float ac = 0.f, ae = 0.f;
    #pragma unroll 8
    for (int k = 0; k < NODE_DIM; ++k) {
      float xk = x[k];
      ac = fmaf(xk, W1c[k * HIDDEN + l], ac);
      ae = fmaf(xk, W1e[k * HIDDEN + l], ae);
    }
    qcon[r * HIDDEN + l] = ac + b1c[l];
    float he = fmaxf(ae + b1e[l], 0.f) * W2e[l];
    #pragma unroll
    for (int off = 32; off > 0; off >>= 1) he += __shfl_xor(he, off);
    if (l == 0) srel[r] = he + b2e[0] + b2c[0];
  }
}

// ---------------------------------------------------------------------------
// Kernel 2: MFMA prep GEMM.  C[100000 x 192] = all_embed @ [W1c|W1s|W1d].
// Block = 8 waves, BM=128 (wave w -> rows m0..m0+15). K=128 via 4 MFMA steps.
// Cols 0..63 -> pcon (fp16, bias folded into qcon); 64..127 -> fused
// relu(.+b1s)@W2s+b2s -> ssrc; 128..191 -> sdst.
// ---------------------------------------------------------------------------
__global__ __launch_bounds__(512) void prep_gemm(
    const float* __restrict__ x,
    const _Float16* __restrict__ wt,      // [192][128] f16, k XOR-swizzled
    const float* __restrict__ b1s, const float* __restrict__ W2s,
    const float* __restrict__ b2s,
    const float* __restrict__ b1d, const float* __restrict__ W2d,
    const float* __restrict__ b2d,
    __half* __restrict__ pcon,
    float* __restrict__ ssrc, float* __restrict__ sdst) {
  __shared__ _Float16 bl[192 * NODE_DIM];       // 48 KiB
  const int wv = threadIdx.x >> 6;              // 0..7
  const int l  = threadIdx.x & 63;
  const int hi = l >> 4;
  const int c  = l & 15;

  // Stage wt -> LDS linearly: 48 chunks of 1 KiB (64 lanes x 16 B); wave w
  // takes chunks w, w+8, ... (LDS dest = uniform base + lane*16).
  {
    const char* g = (const char*)wt;
    #pragma unroll
    for (int i = 0; i < 6; ++i) {
      const int chunk = (i * 8 + wv) << 10;
      __builtin_amdgcn_global_load_lds(
          (const __attribute__((address_space(1))) void*)(g + chunk + l * 16),
          (__attribute__((address_space(3))) void*)((char*)bl + chunk),
          16, 0, 0);
    }
  }

  // A fragments: lane holds row m0+(l&15), k = s*32 + hi*8 .. +7 (f32->f16).
  const int m0   = blockIdx.x * 128 + wv * 16;
  const int arow = m0 + c;
  const int rowc = arow < N_NODES ? arow : N_NODES - 1;
  const float* xr = x + (size_t)rowc * NODE_DIM + hi * 8;
  f16x8 a[4];
  #pragma unroll
  for (int s = 0; s < 4; ++s) {
    float4 u0 = *(const float4*)(xr + s * 32);
    float4 u1 = *(const float4*)(xr + s * 32 + 4);
    f16x8 av;
    av[0] = (_Float16)u0.x; av[1] = (_Float16)u0.y;
    av[2] = (_Float16)u0.z; av[3] = (_Float16)u0.w;
    av[4] = (_Float16)u1.x; av[5] = (_Float16)u1.y;
    av[6] = (_Float16)u1.z; av[7] = (_Float16)u1.w;
    a[s] = av;
  }

  __syncthreads();   // drains global_load_lds (vmcnt) + barrier

  f32x4 acc[12];
  #pragma unroll
  for (int i = 0; i < 12; ++i) acc[i] = (f32x4){0.f, 0.f, 0.f, 0.f};

  #pragma unroll
  for (int tt = 0; tt < 12; ++tt) {
    const int n = tt * 16 + c;
    const int nbase = n * NODE_DIM;
    #pragma unroll
    for (int s = 0; s < 4; ++s) {
      const int ks = (s * 32 + hi * 8) ^ ((n & 7) << 3);
      f16x8 b = *(const f16x8*)(&bl[nbase + ks]);
      acc[tt] = __builtin_amdgcn_mfma_f32_16x16x32_f16(a[s], b, acc[tt], 0, 0, 0);
    }
  }

  // ---- epilogue ----
  // con: D[row][col]: col = c (hidden tt*16+c), row = hi*4+g
  #pragma unroll
  for (int tt = 0; tt < 4; ++tt) {
    #pragma unroll
    for (int g = 0; g < 4; ++g) {
      const int row = m0 + hi * 4 + g;
      if (row < N_NODES)
        pcon[(size_t)row * HIDDEN + tt * 16 + c] = __float2half(acc[tt][g]);
    }
  }
  // src / dst: fused relu(acc+b1)*W2, reduce over 64 cols (4 tiles x 16 lanes)
  float ps[4] = {0.f, 0.f, 0.f, 0.f};
  float pd[4] = {0.f, 0.f, 0.f, 0.f};
  #pragma unroll
  for (int tt = 0; tt < 4; ++tt) {
    const int h = tt * 16 + c;
    const float b1sv = b1s[h], w2sv = W2s[h];
    const float b1dv = b1d[h], w2dv = W2d[h];
    #pragma unroll
    for (int g = 0; g < 4; ++g) {
      ps[g] += fmaxf(acc[4 + tt][g] + b1sv, 0.f) * w2sv;
      pd[g] += fmaxf(acc[8 + tt][g] + b1dv, 0.f) * w2dv;
    }
  }
  #pragma unroll
  for (int off = 1; off < 16; off <<= 1) {
    #pragma unroll
    for (int g = 0; g < 4; ++g) {
      ps[g] += __shfl_xor(ps[g], off);
      pd[g] += __shfl_xor(pd[g], off);
    }
  }
  if (c == 0) {
    const float bs = b2s[0], bd = b2d[0];
    #pragma unroll
    for (int g = 0; g < 4; ++g) {
      const int row = m0 + hi * 4 + g;
      if (row < N_NODES) { ssrc[row] = ps[g] + bs; sdst[row] = pd[g] + bd; }
    }
  }
}

// ---------------------------------------------------------------------------
// Edge kernel: 8 lanes/edge; weight = relu(p[src]+p[dst]+q[r]) @ W2c
//            + ssrc[src] + sdst[dst] + srel[r]   (biases pre-folded)
// Tail uses HW transcendentals (v_log/v_exp/v_rcp, ~1 ulp — threshold 2e-2).
// ---------------------------------------------------------------------------
__global__ __launch_bounds__(256) void edge_kernel(
    const int*   __restrict__ edge_index,
    const int*   __restrict__ edge_type,
    const float* __restrict__ u,
    const __half* __restrict__ pcon,
    const float* __restrict__ ssrc,
    const float* __restrict__ sdst,
    const float* __restrict__ qcon,
    const float* __restrict__ srel,
    const float* __restrict__ W2c,
    float* __restrict__ out) {
  const int tid = blockIdx.x * 256 + threadIdx.x;   // < 8M, fits int
  const int e   = tid >> 3;
  const int sub = tid & 7;

  const int src = edge_index[e];
  const int dst = edge_index[N_EDGESC + e];
  const int r   = edge_type[e];

  const int soff = src * HIDDEN + sub * 8;   // < 6.4M, 32-bit
  const int doff = dst * HIDDEN + sub * 8;

  uint4 us = *(const uint4*)(pcon + soff);
  uint4 ut = *(const uint4*)(pcon + doff);
  const float4 q0 = *(const float4*)(qcon + r * HIDDEN + sub * 8);
  const float4 q1 = *(const float4*)(qcon + r * HIDDEN + sub * 8 + 4);
  const float4 w0 = *(const float4*)(W2c + sub * 8);
  const float4 w1 = *(const float4*)(W2c + sub * 8 + 4);

  const __half2* hs = (const __half2*)&us;
  const __half2* ht = (const __half2*)&ut;
  const float qv[8] = {q0.x, q0.y, q0.z, q0.w, q1.x, q1.y, q1.z, q1.w};
  const float wv[8] = {w0.x, w0.y, w0.z, w0.w, w1.x, w1.y, w1.z, w1.w};

  float s = 0.f;
  #pragma unroll
  for (int j = 0; j < 4; ++j) {
    float2 fs = __half22float2(hs[j]);
    float2 ft = __half22float2(ht[j]);
    s += fmaxf(fs.x + ft.x + qv[2 * j],     0.f) * wv[2 * j];
    s += fmaxf(fs.y + ft.y + qv[2 * j + 1], 0.f) * wv[2 * j + 1];
  }
  s += __shfl_xor(s, 1);
  s += __shfl_xor(s, 2);
  s += __shfl_xor(s, 4);

  if (sub == 0) {
    float wsum = s + ssrc[src] + sdst[dst] + srel[r];
    float uu   = u[e];
    float eps  = fmaf(2.f * BIASF - 1.f, uu, 1.f - BIASF);   // eps
    float ome  = fmaf(1.f - 2.f * BIASF, uu, BIASF);         // 1 - eps
    float g    = __logf(eps) - __logf(ome);                  // v_log based
    float z    = (g + wsum) * (1.f / TEMPERATURE);
    out[e] = __builtin_amdgcn_rcpf(1.f + __expf(-z));        // v_exp + v_rcp
  }
}

extern "C" void kernel_launch(void* const* d_in, const int* in_sizes, int n_in,
                              void* d_out, int out_size, void* d_ws, size_t ws_size,
                              hipStream_t stream) {
  const int*   edge_index = (const int*)d_in[0];
  const int*   edge_type  = (const int*)d_in[1];
  const float* all_embed  = (const float*)d_in[2];
  const float* rel_emb    = (const float*)d_in[3];
  const float* u          = (const float*)d_in[4];
  const float* W1_src = (const float*)d_in[5];
  const float* b1_src = (const float*)d_in[6];
  const float* W2_src = (const float*)d_in[7];
  const float* b2_src = (const float*)d_in[8];
  const float* W1_dst = (const float*)d_in[9];
  const float* b1_dst = (const float*)d_in[10];
  const float* W2_dst = (const float*)d_in[11];
  const float* b2_dst = (const float*)d_in[12];
  const float* W1_edge = (const float*)d_in[13];
  const float* b1_edge = (const float*)d_in[14];
  const float* W2_edge = (const float*)d_in[15];
  const float* b2_edge = (const float*)d_in[16];
  const float* W1_con = (const float*)d_in[17];
  const float* b1_con = (const float*)d_in[18];
  const float* W2_con = (const float*)d_in[19];
  const float* b2_con = (const float*)d_in[20];

  char* ws = (char*)d_ws;
  __half*   pcon = (__half*)ws;                                  // 100000*64 fp16
  float*    ssrc = (float*)(ws + (size_t)N_NODES * HIDDEN * 2);  // 100000
  float*    sdst = ssrc + N_NODES;                               // 100000
  float*    qcon = sdst + N_NODES;                               // 50*64
  float*    srel = qcon + N_RELS * HIDDEN;                       // 50
  _Float16* wt   = (_Float16*)(srel + N_RELS);                   // 192*128 f16

  prep_small<<<96 + (N_RELS + 3) / 4, 256, 0, stream>>>(
      W1_con, W1_src, W1_dst, rel_emb, b1_con,
      W1_edge, b1_edge, W2_edge, b2_edge, b2_con,
      wt, qcon, srel);

  prep_gemm<<<(N_NODES + 127) / 128, 512, 0, stream>>>(
      all_embed, wt,
      b1_src, W2_src, b2_src, b1_dst, W2_dst, b2_dst,
      pcon, ssrc, sdst);

  edge_kernel<<<(N_EDGESC * 8) / 256, 256, 0, stream>>>(
      edge_index, edge_type, u, pcon, ssrc, sdst, qcon, srel, W2_con,
      (float*)d_out);
}